// Round 18
// baseline (57.013 us; speedup 1.0000x reference)
//
#include <hip/hip_runtime.h>

#define NN 2048
#define GG 64
#define TS 128
#define NT (NN / TS)                 // 16 tiles
#define NPAIR (NT * (NT + 1) / 2)    // 136 tile pairs
#define MAXE 14336                   // per-image CSR entry cap
#define CAPBLK 2048                  // per-block edge region (real max ~50)
#define STH 1024                     // scan threads (16 waves)
#define NWAVE (STH / 64)

typedef unsigned long long u64;
typedef unsigned short u16;
typedef unsigned int u32;

__device__ __forceinline__ float iou4(float4 a, float4 b) {
    float w = fminf(a.z, b.z) - fmaxf(a.x, b.x) + 1.0f;
    float h = fminf(a.w, b.w) - fmaxf(a.y, b.y) + 1.0f;
    w = fmaxf(w, 0.0f);
    h = fmaxf(h, 0.0f);
    float ov = w * h;
    float aa = (a.z - a.x + 1.0f) * (a.w - a.y + 1.0f);
    float ab = (b.z - b.x + 1.0f) * (b.w - b.y + 1.0f);
    return ov / (aa + ab - ov);
}

__device__ __forceinline__ float wredf(float v) {
    for (int o = 32; o > 0; o >>= 1) v += __shfl_down(v, o);
    return v;
}
__device__ __forceinline__ int wredi(int v) {
    for (int o = 32; o > 0; o >>= 1) v += __shfl_down(v, o);
    return v;
}
__device__ __forceinline__ u64 wredmin64(u64 v) {
    for (int o = 32; o > 0; o >>= 1) {
        u64 w = __shfl_down(v, o);
        v = (w < v) ? w : v;
    }
    return v;
}

// selection order: earlier = higher score, tie -> lower original index (scores >= 0).
__device__ __forceinline__ bool earlier(u32 sa, int a, u32 sb, int b) {
    return (sa > sb) || (sa == sb && a < b);
}
__device__ __forceinline__ u64 make_key(u32 sbits, int j) {
    return ((u64)sbits << 32) | (u64)(NN - 1 - j);
}
__device__ __forceinline__ float4 load_box(const float* pb, int j) {
    return make_float4(pb[j * 5 + 0], pb[j * 5 + 1], pb[j * 5 + 2], pb[j * 5 + 3]);
}

// ---------------- K1: pair phase -> per-block edge regions + SoA export (diagonal blocks) ----------------
__global__ __launch_bounds__(256) void pair_kernel(const int* __restrict__ gt_inds,
                                                   const float* __restrict__ props,
                                                   int* __restrict__ counts, u32* __restrict__ edges,
                                                   float4* __restrict__ sbox, u32* __restrict__ sscB,
                                                   int* __restrict__ sgt,
                                                   float* __restrict__ acc, u32* __restrict__ ctr2) {
    const int im = blockIdx.x / NPAIR;
    const int p = blockIdx.x % NPAIR;
    int q = p;
    int ta = 0;
    while (q >= NT - ta) { q -= NT - ta; ++ta; }
    const int tb = ta + q;
    const float* pb = props + (size_t)im * NN * 5;
    const int* gbi = gt_inds + (size_t)im * NN;
    const int base = im * NN;

    __shared__ float4 Abox[TS], Bbox[TS];
    __shared__ u32 Asc[TS], Bsc[TS];
    __shared__ int Ag[TS], Bg[TS];
    __shared__ u32 ebuf[CAPBLK];
    __shared__ int lcnt;
    const int tid = threadIdx.x;
    if (tid == 0) lcnt = 0;
    if (blockIdx.x == 0 && tid == 0) { acc[0] = 0.f; acc[1] = 0.f; *ctr2 = 0u; }

    for (int t = tid; t < 2 * TS; t += 256) {
        int half = t >> 7, r = t & (TS - 1);
        int j = (half ? tb : ta) * TS + r;
        float4 bxv = load_box(pb, j);
        u32 sb = __float_as_uint(pb[j * 5 + 4]);
        int g = gbi[j];
        if (half == 0) { Abox[r] = bxv; Asc[r] = sb; Ag[r] = g; }
        else           { Bbox[r] = bxv; Bsc[r] = sb; Bg[r] = g; }
    }
    __syncthreads();

    // ---- diagonal blocks export their tile as packed SoA (covers all tiles once) ----
    if (ta == tb && tid < TS) {
        sbox[base + ta * TS + tid] = Abox[tid];
        sscB[base + ta * TS + tid] = Asc[tid];
        sgt[base + ta * TS + tid] = Ag[tid];
    }

    const int pr = tid & (TS - 1);      // row in tile A
    const int half = tid >> 7;          // column half in tile B
    const float4 rb = Abox[pr];
    const u32 rs = Asc[pr];
    const int i = ta * TS + pr;
    if (Ag[pr] >= 0) {
        #pragma unroll 4
        for (int k = 0; k < TS / 2; ++k) {
            int jl = half * (TS / 2) + k;
            if (ta == tb && jl <= pr) continue;   // each unordered pair once
            if (Bg[jl] < 0) continue;
            float v = iou4(rb, Bbox[jl]);
            if (v > 0.5f) {
                int j = tb * TS + jl;
                int late, early;
                if (earlier(rs, i, Bsc[jl], j)) { late = j; early = i; }
                else                            { late = i; early = j; }
                int slot = atomicAdd(&lcnt, 1);            // LDS atomic only
                if (slot < CAPBLK) ebuf[slot] = ((u32)late << 16) | (u32)early;
            }
        }
    }
    __syncthreads();
    const int n = min(lcnt, CAPBLK);
    if (tid == 0) counts[blockIdx.x] = n;                   // unconditional: no zero-init needed
    u32* ge = edges + (size_t)blockIdx.x * CAPBLK;
    for (int e = tid; e < n; e += 256) ge[e] = ebuf[e];     // coalesced copy
}

// ---------------- K2: fully LDS-resident CSR + single-wave fixpoint + attribution ----------------
union SumWl {
    float sumA[NN];                   // 8 KB (attribution only)
    u16 wl[2][NN];                    // fixpoint worklists
};

__global__ __launch_bounds__(STH) void scan_kernel(const float* __restrict__ gt_boxes,
                                                   const float4* __restrict__ sbox,
                                                   const u32* __restrict__ sscB,
                                                   const int* __restrict__ sgt,
                                                   const int* __restrict__ counts, const u32* __restrict__ edges,
                                                   float* __restrict__ acc, u32* __restrict__ ctr2,
                                                   float* __restrict__ out, int B) {
    __shared__ float4 bx[NN];             // 32 KB — all boxes resident
    __shared__ u32 scoreL[NN];            // 8 KB
    __shared__ SumWl u;                   // 8 KB
    __shared__ int cw[NN];                // 8 KB: count -> cursor -> cntA
    __shared__ u16 eoff[NN + 2];          // 4.1 KB
    __shared__ u16 ent[MAXE];             // 28 KB
    __shared__ unsigned char st[NN];      // 2 KB
    __shared__ unsigned char hk[NN];      // 2 KB
    __shared__ signed char gtL[NN];       // 2 KB
    __shared__ int rcnt[NPAIR];           // 544 B
    __shared__ float4 gtb[GG];            // 1 KB
    __shared__ float4 recbox[GG];         // 1 KB
    __shared__ u64 firstk[GG];            // 0.5 KB
    __shared__ int wtot[NWAVE];
    __shared__ int s_cnt;
    __shared__ u64 s_minkey;
    __shared__ int s_pos, s_qcnt, s_pcnt;
    __shared__ float s_tpush, s_tpull;

    const int im = blockIdx.x, tid = threadIdx.x;
    const int lane = tid & 63, wid = tid >> 6;
    const int base = im * NN;
    volatile unsigned char* vst = st;

    if (tid == 0) {
        s_pos = 0; s_qcnt = 0; s_pcnt = 0; s_tpush = 0.f; s_tpull = 0.f; s_minkey = ~0ull;
        s_cnt = 0;
    }
    if (tid < GG) {
        firstk[tid] = 0ull;
        gtb[tid] = ((const float4*)(gt_boxes + (size_t)im * GG * 4))[tid];
    }
    if (tid < NPAIR) rcnt[tid] = counts[im * NPAIR + tid];

    // ---- stage SoA into LDS (fully coalesced) ----
    int lpos = 0;
    for (int j = tid; j < NN; j += STH) {
        bx[j] = sbox[base + j];
        scoreL[j] = sscB[base + j];
        int g = sgt[base + j];
        gtL[j] = (signed char)((g < 0) ? -1 : g);
        st[j] = (g >= 0) ? 0 : 2;
        lpos += (g >= 0) ? 1 : 0;
        cw[j] = 0; hk[j] = 0;
    }
    lpos = wredi(lpos);
    if (lane == 0 && lpos) atomicAdd(&s_pos, lpos);
    __syncthreads();

    // ---- CSR count pass: one wave per edge region ----
    for (int r = wid; r < NPAIR; r += NWAVE) {
        int cr = rcnt[r];
        const u32* ge = edges + (size_t)(im * NPAIR + r) * CAPBLK;
        for (int e = lane; e < cr; e += 64) atomicAdd(&cw[ge[e] >> 16], 1);
    }
    __syncthreads();
    {   // block-wide exclusive prefix sum over 2048 counts (2 per thread, 16 waves)
        int j0 = tid * 2;
        int c0 = cw[j0], c1 = cw[j0 + 1];
        int s = c0 + c1;
        int incl = s;
        for (int o = 1; o < 64; o <<= 1) {
            int v = __shfl_up(incl, o);
            if (lane >= o) incl += v;
        }
        if (lane == 63) wtot[wid] = incl;
        __syncthreads();
        int wpre = 0;
        for (int wq = 0; wq < wid; ++wq) wpre += wtot[wq];
        int excl = wpre + incl - s;
        eoff[j0] = (u16)excl;
        eoff[j0 + 1] = (u16)(excl + c0);
        if (tid == STH - 1) eoff[NN] = (u16)(excl + s);
        cw[j0] = excl;
        cw[j0 + 1] = excl + c0;
    }
    __syncthreads();
    // ---- CSR scatter pass ----
    for (int r = wid; r < NPAIR; r += NWAVE) {
        int cr = rcnt[r];
        const u32* ge = edges + (size_t)(im * NPAIR + r) * CAPBLK;
        for (int e = lane; e < cr; e += 64) {
            u32 x = ge[e];
            int pos = atomicAdd(&cw[x >> 16], 1);
            ent[pos] = (u16)(x & 0xffffu);
        }
    }
    __syncthreads();

    // ---- fixpoint round 1: full sweep, compact unresolved into worklist 0 ----
    for (int j = tid; j < NN; j += STH) {
        if (st[j] != 0) continue;
        int e0 = eoff[j], e1 = eoff[j + 1];
        bool anyK = false, anyU = false;
        for (int e = e0; e < e1; ++e) {
            unsigned char s = vst[ent[e]];
            anyK |= (s == 1);
            anyU |= (s == 0);
        }
        if (anyK) st[j] = 2;
        else if (!anyU) st[j] = 1;
        else { int pos = atomicAdd(&s_cnt, 1); u.wl[0][pos] = (u16)j; }
    }
    __syncthreads();

    // ---- fixpoint tail: SINGLE WAVE, zero barriers (wave-lockstep LDS visibility) ----
    if (wid == 0) {
        int nwl = s_cnt;
        int src = 0;
        while (nwl > 0) {
            int dst = src ^ 1;
            int nnew = 0;
            int nt = (nwl + 63) >> 6;
            for (int t = 0; t < nt; ++t) {
                int w = t * 64 + lane;
                bool keep = false;
                int j = 0;
                if (w < nwl) {
                    j = u.wl[src][w];
                    if (st[j] == 0) {
                        int e0 = eoff[j], e1 = eoff[j + 1];
                        bool anyK = false, anyU = false;
                        for (int e = e0; e < e1; ++e) {
                            unsigned char s = vst[ent[e]];
                            anyK |= (s == 1);
                            anyU |= (s == 0);
                        }
                        if (anyK) st[j] = 2;
                        else if (!anyU) st[j] = 1;
                        else keep = true;       // predecessors still unresolved
                    }
                }
                u64 m = __ballot(keep);
                if (keep) {
                    int pos = __popcll(m & ((1ull << lane) - 1ull));
                    u.wl[dst][nnew + pos] = (u16)j;
                }
                nnew += __popcll(m);            // uniform across lanes
            }
            // >=1 resolves per pass (topologically-first unresolved has all preds resolved)
            nwl = nnew;
            src = dst;
        }
    }
    __syncthreads();

    // ---- merged sweep: zero sumA/cw (worklists dead) + kept bookkeeping (pass 1a) ----
    u64 lmin = ~0ull;
    for (int j = tid; j < NN; j += STH) {
        u.sumA[j] = 0.f; cw[j] = 0;
        if (st[j] == 1) {
            u64 kj = make_key(scoreL[j], j);
            if (kj < lmin) lmin = kj;
            atomicMax(&firstk[gtL[j]], kj);      // 64 distinct LDS addresses
        }
    }
    lmin = wredmin64(lmin);
    if (lane == 0 && lmin != ~0ull) atomicMin(&s_minkey, lmin);
    __syncthreads();

    // ---- stage firstk boxes (pull partners) ----
    if (tid < GG) {
        u64 fk = firstk[tid];
        if (fk) recbox[tid] = bx[(NN - 1) - (int)(fk & 0xffffffffu)];
    }

    // ---- pass 1b: killer attribution (killed positives only; all LDS) ----
    for (int j = tid; j < NN; j += STH) {
        int g = gtL[j];
        if (st[j] != 2 || g < 0) continue;
        int e0 = eoff[j], e1 = eoff[j + 1];
        int ki = -1; u32 ks = 0;
        for (int e = e0; e < e1; ++e) {
            int ii = ent[e];
            if (st[ii] == 1 && (ki < 0 || earlier(scoreL[ii], ii, ks, ki))) { ki = ii; ks = scoreL[ii]; }
        }
        if (ki < 0) continue;             // cannot happen for a killed positive
        hk[ki] = 1;                       // benign race: all write 1
        float v = iou4(bx[ki], bx[j]);
        int gi = gtL[ki];
        if (g != gi && v > iou4(gtb[gi], gtb[g])) {
            atomicAdd(&cw[ki], 1);
            atomicAdd(&u.sumA[ki], -logf(1.5f - v) * __uint_as_float(scoreL[j]));
        }
    }
    __syncthreads();

    // ---- pass 2: accumulation over kept selections (order-free) ----
    float ltpush = 0.f, ltpull = 0.f;
    int lqcnt = 0, lpcnt = 0;
    const u64 minkey = s_minkey;
    for (int i = tid; i < NN; i += STH) {
        if (st[i] != 1) continue;
        int g = gtL[i];
        u64 ky = make_key(scoreL[i], i);
        u64 fk = firstk[g];
        bool add = (ky != minkey) || (hk[i] != 0);   // any(alive_p) at this selection
        int c = cw[i];
        bool hr = fk > ky;                            // earlier kept with same gt
        if (add && c > 0) ltpush += u.sumA[i] / (float)c;
        if (add) lqcnt += c;
        if (hr) ++lpcnt;                              // counted even when !add (matches ref)
        if (add && hr) {
            float v = iou4(bx[i], recbox[g]);
            ltpull += -logf(fmaxf(v, 1e-6f)) * __uint_as_float(scoreL[i]);
        }
    }
    ltpush = wredf(ltpush); ltpull = wredf(ltpull);
    lqcnt = wredi(lqcnt); lpcnt = wredi(lpcnt);
    if (lane == 0) {
        if (ltpush != 0.f) atomicAdd(&s_tpush, ltpush);
        if (ltpull != 0.f) atomicAdd(&s_tpull, ltpull);
        if (lqcnt) atomicAdd(&s_qcnt, lqcnt);
        if (lpcnt) atomicAdd(&s_pcnt, lpcnt);
    }
    __syncthreads();

    // ---- cross-image finalize: last-finishing block writes the B-mean ----
    if (tid == 0) {
        float valid = (s_pos > 1) ? 1.0f : 0.0f;
        float push_b = s_tpush / ((float)s_qcnt + 1e-6f) * valid;
        float pull_b = s_tpull / ((float)s_pcnt + 1e-6f) * valid;
        atomicAdd(&acc[0], push_b);
        atomicAdd(&acc[1], pull_b);
        __threadfence();
        u32 old = atomicAdd(ctr2, 1u);
        if (old == (u32)(B - 1)) {
            float ps = atomicAdd(&acc[0], 0.0f);   // coherent device-scope read
            float pl = atomicAdd(&acc[1], 0.0f);
            float inv = 1.0f / (float)B;
            out[0] = ps * inv * 1.0f;  // push_loss * PUSH_W
            out[1] = pl * inv * 1.0f;  // pull_loss * PULL_W
        }
    }
}

extern "C" void kernel_launch(void* const* d_in, const int* in_sizes, int n_in,
                              void* d_out, int out_size, void* d_ws, size_t ws_size,
                              hipStream_t stream) {
    // inputs: 0=gt_inds(B*N i32), 1=anchor_gt_inds(B*N i32),
    //         2=gt_bboxes(B*G*4 f32), 3=proposal_list(B*N*5 f32)
    const int B = in_sizes[0] / NN;
    const int* anchor_gt = (const int*)d_in[1];
    const float* gtb = (const float*)d_in[2];
    const float* props = (const float*)d_in[3];

    // ---- workspace: [acc|ctr2|pad][counts][sbox][sscB][sgt][edges] ----
    char* w = (char*)d_ws;
    float* acc = (float*)w;
    u32* ctr2 = (u32*)(w + 8);
    size_t o = 128;
    int* counts = (int*)(w + o);   o += ((size_t)B * NPAIR * 4 + 127) & ~(size_t)127;
    float4* sbox = (float4*)(w + o); o += (size_t)B * NN * 16;
    u32* sscB = (u32*)(w + o);     o += (size_t)B * NN * 4;
    int* sgt = (int*)(w + o);      o += (size_t)B * NN * 4;
    u32* edges = (u32*)(w + o);

    pair_kernel<<<dim3(B * NPAIR), dim3(256), 0, stream>>>(anchor_gt, props, counts, edges,
                                                           sbox, sscB, sgt, acc, ctr2);
    scan_kernel<<<dim3(B), dim3(STH), 0, stream>>>(gtb, sbox, sscB, sgt, counts, edges,
                                                   acc, ctr2, (float*)d_out, B);
}

// Round 19
// 47.699 us; speedup vs baseline: 1.1953x; 1.1953x over previous
//
#include <hip/hip_runtime.h>

#define NN 2048
#define GG 64
#define TS 128
#define NT (NN / TS)                 // 16 tiles
#define NPAIR (NT * (NT + 1) / 2)    // 136 tile pairs
#define MAXE 14336                   // per-image CSR entry cap
#define CAPBLK 2048                  // per-block edge region (real max ~50)
#define STH 1024                     // scan threads (16 waves)
#define NWAVE (STH / 64)

typedef unsigned long long u64;
typedef unsigned short u16;
typedef unsigned int u32;

__device__ __forceinline__ float iou4(float4 a, float4 b) {
    float w = fminf(a.z, b.z) - fmaxf(a.x, b.x) + 1.0f;
    float h = fminf(a.w, b.w) - fmaxf(a.y, b.y) + 1.0f;
    w = fmaxf(w, 0.0f);
    h = fmaxf(h, 0.0f);
    float ov = w * h;
    float aa = (a.z - a.x + 1.0f) * (a.w - a.y + 1.0f);
    float ab = (b.z - b.x + 1.0f) * (b.w - b.y + 1.0f);
    return ov / (aa + ab - ov);
}

__device__ __forceinline__ float wredf(float v) {
    for (int o = 32; o > 0; o >>= 1) v += __shfl_down(v, o);
    return v;
}
__device__ __forceinline__ int wredi(int v) {
    for (int o = 32; o > 0; o >>= 1) v += __shfl_down(v, o);
    return v;
}
__device__ __forceinline__ u64 wredmin64(u64 v) {
    for (int o = 32; o > 0; o >>= 1) {
        u64 w = __shfl_down(v, o);
        v = (w < v) ? w : v;
    }
    return v;
}

// selection order: earlier = higher score, tie -> lower original index (scores >= 0).
__device__ __forceinline__ bool earlier(u32 sa, int a, u32 sb, int b) {
    return (sa > sb) || (sa == sb && a < b);
}
__device__ __forceinline__ u64 make_key(u32 sbits, int j) {
    return ((u64)sbits << 32) | (u64)(NN - 1 - j);
}
__device__ __forceinline__ float4 load_box(const float* pb, int j) {
    return make_float4(pb[j * 5 + 0], pb[j * 5 + 1], pb[j * 5 + 2], pb[j * 5 + 3]);
}

// ---------------- K1: pair phase -> per-block edge regions + SoA export (diagonal blocks) ----------------
__global__ __launch_bounds__(256) void pair_kernel(const int* __restrict__ gt_inds,
                                                   const float* __restrict__ props,
                                                   int* __restrict__ counts, u32* __restrict__ edges,
                                                   float4* __restrict__ sbox, u32* __restrict__ sscB,
                                                   int* __restrict__ sgt,
                                                   float* __restrict__ acc, u32* __restrict__ ctr2) {
    const int im = blockIdx.x / NPAIR;
    const int p = blockIdx.x % NPAIR;
    int q = p;
    int ta = 0;
    while (q >= NT - ta) { q -= NT - ta; ++ta; }
    const int tb = ta + q;
    const float* pb = props + (size_t)im * NN * 5;
    const int* gbi = gt_inds + (size_t)im * NN;
    const int base = im * NN;

    __shared__ float4 Abox[TS], Bbox[TS];
    __shared__ u32 Asc[TS], Bsc[TS];
    __shared__ int Ag[TS], Bg[TS];
    __shared__ u32 ebuf[CAPBLK];
    __shared__ int lcnt;
    const int tid = threadIdx.x;
    if (tid == 0) lcnt = 0;
    if (blockIdx.x == 0 && tid == 0) { acc[0] = 0.f; acc[1] = 0.f; *ctr2 = 0u; }

    for (int t = tid; t < 2 * TS; t += 256) {
        int half = t >> 7, r = t & (TS - 1);
        int j = (half ? tb : ta) * TS + r;
        float4 bxv = load_box(pb, j);
        u32 sb = __float_as_uint(pb[j * 5 + 4]);
        int g = gbi[j];
        if (half == 0) { Abox[r] = bxv; Asc[r] = sb; Ag[r] = g; }
        else           { Bbox[r] = bxv; Bsc[r] = sb; Bg[r] = g; }
    }
    __syncthreads();

    // ---- diagonal blocks export their tile as packed SoA (covers all tiles once) ----
    if (ta == tb && tid < TS) {
        sbox[base + ta * TS + tid] = Abox[tid];
        sscB[base + ta * TS + tid] = Asc[tid];
        sgt[base + ta * TS + tid] = Ag[tid];
    }

    const int pr = tid & (TS - 1);      // row in tile A
    const int half = tid >> 7;          // column half in tile B
    const float4 rb = Abox[pr];
    const u32 rs = Asc[pr];
    const int i = ta * TS + pr;
    if (Ag[pr] >= 0) {
        #pragma unroll 4
        for (int k = 0; k < TS / 2; ++k) {
            int jl = half * (TS / 2) + k;
            if (ta == tb && jl <= pr) continue;   // each unordered pair once
            if (Bg[jl] < 0) continue;
            float v = iou4(rb, Bbox[jl]);
            if (v > 0.5f) {
                int j = tb * TS + jl;
                int late, early;
                if (earlier(rs, i, Bsc[jl], j)) { late = j; early = i; }
                else                            { late = i; early = j; }
                int slot = atomicAdd(&lcnt, 1);            // LDS atomic only
                if (slot < CAPBLK) ebuf[slot] = ((u32)late << 16) | (u32)early;
            }
        }
    }
    __syncthreads();
    const int n = min(lcnt, CAPBLK);
    if (tid == 0) counts[blockIdx.x] = n;                   // unconditional: no zero-init needed
    u32* ge = edges + (size_t)blockIdx.x * CAPBLK;
    for (int e = tid; e < n; e += 256) ge[e] = ebuf[e];     // coalesced copy
}

// ---------------- K2: fully LDS-resident CSR + fixpoint + attribution + finalize ----------------
union SumWl {
    float sumA[NN];                   // 8 KB (attribution only)
    u16 wl[2][NN];                    // fixpoint worklists
};

__global__ __launch_bounds__(STH) void scan_kernel(const float* __restrict__ gt_boxes,
                                                   const float4* __restrict__ sbox,
                                                   const u32* __restrict__ sscB,
                                                   const int* __restrict__ sgt,
                                                   const int* __restrict__ counts, const u32* __restrict__ edges,
                                                   float* __restrict__ acc, u32* __restrict__ ctr2,
                                                   float* __restrict__ out, int B) {
    __shared__ float4 bx[NN];             // 32 KB — all boxes resident
    __shared__ u32 scoreL[NN];            // 8 KB
    __shared__ SumWl u;                   // 8 KB
    __shared__ int cw[NN];                // 8 KB: count -> cursor -> cntA
    __shared__ u16 eoff[NN + 2];          // 4.1 KB
    __shared__ u16 ent[MAXE];             // 28 KB
    __shared__ unsigned char st[NN];      // 2 KB
    __shared__ unsigned char hk[NN];      // 2 KB
    __shared__ signed char gtL[NN];       // 2 KB
    __shared__ int rcnt[NPAIR];           // 544 B
    __shared__ float4 gtb[GG];            // 1 KB
    __shared__ float4 recbox[GG];         // 1 KB
    __shared__ u64 firstk[GG];            // 0.5 KB
    __shared__ int wtot[NWAVE];
    __shared__ int s_cnt[2];
    __shared__ u64 s_minkey;
    __shared__ int s_pos, s_qcnt, s_pcnt;
    __shared__ float s_tpush, s_tpull;

    const int im = blockIdx.x, tid = threadIdx.x;
    const int lane = tid & 63, wid = tid >> 6;
    const int base = im * NN;
    volatile unsigned char* vst = st;

    if (tid == 0) {
        s_pos = 0; s_qcnt = 0; s_pcnt = 0; s_tpush = 0.f; s_tpull = 0.f; s_minkey = ~0ull;
        s_cnt[0] = 0; s_cnt[1] = 0;
    }
    if (tid < GG) {
        firstk[tid] = 0ull;
        gtb[tid] = ((const float4*)(gt_boxes + (size_t)im * GG * 4))[tid];
    }
    if (tid < NPAIR) rcnt[tid] = counts[im * NPAIR + tid];

    // ---- stage SoA into LDS (fully coalesced) ----
    int lpos = 0;
    for (int j = tid; j < NN; j += STH) {
        bx[j] = sbox[base + j];
        scoreL[j] = sscB[base + j];
        int g = sgt[base + j];
        gtL[j] = (signed char)((g < 0) ? -1 : g);
        st[j] = (g >= 0) ? 0 : 2;
        lpos += (g >= 0) ? 1 : 0;
        cw[j] = 0; hk[j] = 0;
    }
    lpos = wredi(lpos);
    if (lane == 0 && lpos) atomicAdd(&s_pos, lpos);
    __syncthreads();

    // ---- CSR count pass: one wave per edge region ----
    for (int r = wid; r < NPAIR; r += NWAVE) {
        int cr = rcnt[r];
        const u32* ge = edges + (size_t)(im * NPAIR + r) * CAPBLK;
        for (int e = lane; e < cr; e += 64) atomicAdd(&cw[ge[e] >> 16], 1);
    }
    __syncthreads();
    {   // block-wide exclusive prefix sum over 2048 counts (2 per thread, 16 waves)
        int j0 = tid * 2;
        int c0 = cw[j0], c1 = cw[j0 + 1];
        int s = c0 + c1;
        int incl = s;
        for (int o = 1; o < 64; o <<= 1) {
            int v = __shfl_up(incl, o);
            if (lane >= o) incl += v;
        }
        if (lane == 63) wtot[wid] = incl;
        __syncthreads();
        int wpre = 0;
        for (int wq = 0; wq < wid; ++wq) wpre += wtot[wq];
        int excl = wpre + incl - s;
        eoff[j0] = (u16)excl;
        eoff[j0 + 1] = (u16)(excl + c0);
        if (tid == STH - 1) eoff[NN] = (u16)(excl + s);
        cw[j0] = excl;
        cw[j0 + 1] = excl + c0;
    }
    __syncthreads();
    // ---- CSR scatter pass ----
    for (int r = wid; r < NPAIR; r += NWAVE) {
        int cr = rcnt[r];
        const u32* ge = edges + (size_t)(im * NPAIR + r) * CAPBLK;
        for (int e = lane; e < cr; e += 64) {
            u32 x = ge[e];
            int pos = atomicAdd(&cw[x >> 16], 1);
            ent[pos] = (u16)(x & 0xffffu);
        }
    }
    __syncthreads();

    // ---- fixpoint round 1: full sweep, compact unresolved into worklist 0 ----
    for (int j = tid; j < NN; j += STH) {
        if (st[j] != 0) continue;
        int e0 = eoff[j], e1 = eoff[j + 1];
        bool anyK = false, anyU = false;
        for (int e = e0; e < e1; ++e) {
            unsigned char s = vst[ent[e]];
            anyK |= (s == 1);
            anyU |= (s == 0);
        }
        if (anyK) st[j] = 2;
        else if (!anyU) st[j] = 1;
        else { int pos = atomicAdd(&s_cnt[0], 1); u.wl[0][pos] = (u16)j; }
    }
    __syncthreads();

    // ---- fixpoint rounds: worklist only, 6 relaxation sub-sweeps per barrier round ----
    int src = 0;
    int nwl = s_cnt[0];
    while (nwl > 0) {
        #pragma unroll
        for (int r = 0; r < 5; ++r) {       // benign-race relaxations (monotone st)
            for (int w = tid; w < nwl; w += STH) {
                int j = u.wl[src][w];
                if (st[j] != 0) continue;
                int e0 = eoff[j], e1 = eoff[j + 1];
                bool anyK = false, anyU = false;
                for (int e = e0; e < e1; ++e) {
                    unsigned char s = vst[ent[e]];
                    anyK |= (s == 1);
                    anyU |= (s == 0);
                }
                if (anyK) st[j] = 2;
                else if (!anyU) st[j] = 1;
            }
        }
        // final sub-sweep: resolve-or-append to the other worklist
        for (int w = tid; w < nwl; w += STH) {
            int j = u.wl[src][w];
            if (st[j] != 0) continue;
            int e0 = eoff[j], e1 = eoff[j + 1];
            bool anyK = false, anyU = false;
            for (int e = e0; e < e1; ++e) {
                unsigned char s = vst[ent[e]];
                anyK |= (s == 1);
                anyU |= (s == 0);
            }
            if (anyK) st[j] = 2;
            else if (!anyU) st[j] = 1;
            else { int pos = atomicAdd(&s_cnt[src ^ 1], 1); u.wl[src ^ 1][pos] = (u16)j; }
        }
        __syncthreads();
        nwl = s_cnt[src ^ 1];
        if (tid == 0) s_cnt[src] = 0;
        src ^= 1;
        __syncthreads();
    }

    // ---- merged sweep: zero sumA/cw (worklists dead) + kept bookkeeping (pass 1a) ----
    u64 lmin = ~0ull;
    for (int j = tid; j < NN; j += STH) {
        u.sumA[j] = 0.f; cw[j] = 0;
        if (st[j] == 1) {
            u64 kj = make_key(scoreL[j], j);
            if (kj < lmin) lmin = kj;
            atomicMax(&firstk[gtL[j]], kj);      // 64 distinct LDS addresses
        }
    }
    lmin = wredmin64(lmin);
    if (lane == 0 && lmin != ~0ull) atomicMin(&s_minkey, lmin);
    __syncthreads();

    // ---- stage firstk boxes (pull partners) ----
    if (tid < GG) {
        u64 fk = firstk[tid];
        if (fk) recbox[tid] = bx[(NN - 1) - (int)(fk & 0xffffffffu)];
    }

    // ---- pass 1b: killer attribution (killed positives only; all LDS) ----
    for (int j = tid; j < NN; j += STH) {
        int g = gtL[j];
        if (st[j] != 2 || g < 0) continue;
        int e0 = eoff[j], e1 = eoff[j + 1];
        int ki = -1; u32 ks = 0;
        for (int e = e0; e < e1; ++e) {
            int ii = ent[e];
            if (st[ii] == 1 && (ki < 0 || earlier(scoreL[ii], ii, ks, ki))) { ki = ii; ks = scoreL[ii]; }
        }
        if (ki < 0) continue;             // cannot happen for a killed positive
        hk[ki] = 1;                       // benign race: all write 1
        float v = iou4(bx[ki], bx[j]);
        int gi = gtL[ki];
        if (g != gi && v > iou4(gtb[gi], gtb[g])) {
            atomicAdd(&cw[ki], 1);
            atomicAdd(&u.sumA[ki], -logf(1.5f - v) * __uint_as_float(scoreL[j]));
        }
    }
    __syncthreads();

    // ---- pass 2: accumulation over kept selections (order-free) ----
    float ltpush = 0.f, ltpull = 0.f;
    int lqcnt = 0, lpcnt = 0;
    const u64 minkey = s_minkey;
    for (int i = tid; i < NN; i += STH) {
        if (st[i] != 1) continue;
        int g = gtL[i];
        u64 ky = make_key(scoreL[i], i);
        u64 fk = firstk[g];
        bool add = (ky != minkey) || (hk[i] != 0);   // any(alive_p) at this selection
        int c = cw[i];
        bool hr = fk > ky;                            // earlier kept with same gt
        if (add && c > 0) ltpush += u.sumA[i] / (float)c;
        if (add) lqcnt += c;
        if (hr) ++lpcnt;                              // counted even when !add (matches ref)
        if (add && hr) {
            float v = iou4(bx[i], recbox[g]);
            ltpull += -logf(fmaxf(v, 1e-6f)) * __uint_as_float(scoreL[i]);
        }
    }
    ltpush = wredf(ltpush); ltpull = wredf(ltpull);
    lqcnt = wredi(lqcnt); lpcnt = wredi(lpcnt);
    if (lane == 0) {
        if (ltpush != 0.f) atomicAdd(&s_tpush, ltpush);
        if (ltpull != 0.f) atomicAdd(&s_tpull, ltpull);
        if (lqcnt) atomicAdd(&s_qcnt, lqcnt);
        if (lpcnt) atomicAdd(&s_pcnt, lpcnt);
    }
    __syncthreads();

    // ---- cross-image finalize: last-finishing block writes the B-mean ----
    if (tid == 0) {
        float valid = (s_pos > 1) ? 1.0f : 0.0f;
        float push_b = s_tpush / ((float)s_qcnt + 1e-6f) * valid;
        float pull_b = s_tpull / ((float)s_pcnt + 1e-6f) * valid;
        atomicAdd(&acc[0], push_b);
        atomicAdd(&acc[1], pull_b);
        __threadfence();
        u32 old = atomicAdd(ctr2, 1u);
        if (old == (u32)(B - 1)) {
            float ps = atomicAdd(&acc[0], 0.0f);   // coherent device-scope read
            float pl = atomicAdd(&acc[1], 0.0f);
            float inv = 1.0f / (float)B;
            out[0] = ps * inv * 1.0f;  // push_loss * PUSH_W
            out[1] = pl * inv * 1.0f;  // pull_loss * PULL_W
        }
    }
}

extern "C" void kernel_launch(void* const* d_in, const int* in_sizes, int n_in,
                              void* d_out, int out_size, void* d_ws, size_t ws_size,
                              hipStream_t stream) {
    // inputs: 0=gt_inds(B*N i32), 1=anchor_gt_inds(B*N i32),
    //         2=gt_bboxes(B*G*4 f32), 3=proposal_list(B*N*5 f32)
    const int B = in_sizes[0] / NN;
    const int* anchor_gt = (const int*)d_in[1];
    const float* gtb = (const float*)d_in[2];
    const float* props = (const float*)d_in[3];

    // ---- workspace: [acc|ctr2|pad][counts][sbox][sscB][sgt][edges] ----
    char* w = (char*)d_ws;
    float* acc = (float*)w;
    u32* ctr2 = (u32*)(w + 8);
    size_t o = 128;
    int* counts = (int*)(w + o);   o += ((size_t)B * NPAIR * 4 + 127) & ~(size_t)127;
    float4* sbox = (float4*)(w + o); o += (size_t)B * NN * 16;
    u32* sscB = (u32*)(w + o);     o += (size_t)B * NN * 4;
    int* sgt = (int*)(w + o);      o += (size_t)B * NN * 4;
    u32* edges = (u32*)(w + o);

    pair_kernel<<<dim3(B * NPAIR), dim3(256), 0, stream>>>(anchor_gt, props, counts, edges,
                                                           sbox, sscB, sgt, acc, ctr2);
    scan_kernel<<<dim3(B), dim3(STH), 0, stream>>>(gtb, sbox, sscB, sgt, counts, edges,
                                                   acc, ctr2, (float*)d_out, B);
}